// Round 7
// baseline (615.858 us; speedup 1.0000x reference)
//
#include <hip/hip_runtime.h>

#define D 256
#define SB 1024
typedef __attribute__((ext_vector_type(8))) short short8;
typedef __attribute__((ext_vector_type(4))) float floatx4;

__device__ __forceinline__ unsigned short f2bf(float f) {
  unsigned int u = __float_as_uint(f);
  u = (u + 0x7FFF + ((u >> 16) & 1)) >> 16;   // RNE
  return (unsigned short)u;
}
__device__ __forceinline__ float bf2f(unsigned short h) {
  return __uint_as_float(((unsigned int)h) << 16);
}

// ---------------- setup kernels ----------------
__global__ __launch_bounds__(256) void k_zero_i(int* __restrict__ p, int n) {
  int i = blockIdx.x * 256 + threadIdx.x;
  if (i < n) p[i] = 0;
}

__global__ __launch_bounds__(256) void k_count_i(const int* __restrict__ dst,
    const int* __restrict__ et, int* __restrict__ cnt, int E, int N) {
  int e = blockIdx.x * 256 + threadIdx.x;
  if (e >= E) return;
  atomicAdd(&cnt[et[e] * N + dst[e]], 1);
}

__global__ __launch_bounds__(256) void k_scan1(const int* __restrict__ in,
    int* __restrict__ bsum, int n) {
  __shared__ int s[256];
  int base = blockIdx.x * SB, t = threadIdx.x;
  int a = 0;
#pragma unroll
  for (int j = 0; j < 4; j++) { int i = base + t * 4 + j; if (i < n) a += in[i]; }
  s[t] = a; __syncthreads();
  for (int o = 128; o > 0; o >>= 1) { if (t < o) s[t] += s[t + o]; __syncthreads(); }
  if (t == 0) bsum[blockIdx.x] = s[0];
}

// parallel single-block exclusive scan over bsum (nb <= 1024)
__global__ __launch_bounds__(256) void k_scan2(int* __restrict__ bsum, int nb,
    int* __restrict__ total_out) {
  __shared__ int s[256];
  int t = threadIdx.x;
  int v[4]; int a = 0;
#pragma unroll
  for (int j = 0; j < 4; j++) {
    int i = t * 4 + j;
    v[j] = (i < nb) ? bsum[i] : 0;
    a += v[j];
  }
  s[t] = a; __syncthreads();
  for (int o = 1; o < 256; o <<= 1) {
    int x_ = (t >= o) ? s[t - o] : 0;
    __syncthreads();
    s[t] += x_;
    __syncthreads();
  }
  int excl = (t > 0) ? s[t - 1] : 0;
#pragma unroll
  for (int j = 0; j < 4; j++) {
    int i = t * 4 + j;
    if (i < nb) { bsum[i] = excl; excl += v[j]; }
  }
  if (t == 255) *total_out = s[255];
}

__global__ __launch_bounds__(256) void k_scan3(const int* __restrict__ in,
    const int* __restrict__ bsum, int* __restrict__ off, int* __restrict__ cur,
    int n) {
  __shared__ int s[256];
  int base = blockIdx.x * SB, t = threadIdx.x;
  int v[4]; int a = 0;
#pragma unroll
  for (int j = 0; j < 4; j++) {
    int i = base + t * 4 + j;
    v[j] = (i < n) ? in[i] : 0;
    a += v[j];
  }
  s[t] = a; __syncthreads();
  for (int o = 1; o < 256; o <<= 1) {
    int x_ = (t >= o) ? s[t - o] : 0;
    __syncthreads();
    s[t] += x_;
    __syncthreads();
  }
  int excl = (t > 0 ? s[t - 1] : 0) + bsum[blockIdx.x];
#pragma unroll
  for (int j = 0; j < 4; j++) {
    int i = base + t * 4 + j;
    if (i < n) { off[i] = excl; cur[i] = excl; excl += v[j]; }
  }
}

__global__ __launch_bounds__(256) void k_place2(const int* __restrict__ src,
    const int* __restrict__ dst, const int* __restrict__ et,
    int* __restrict__ cur, int* __restrict__ es, int E, int N) {
  int e = blockIdx.x * 256 + threadIdx.x;
  if (e >= E) return;
  int pos = atomicAdd(&cur[et[e] * N + dst[e]], 1);
  es[pos] = src[e];
}

__global__ __launch_bounds__(256) void k_bounds(const int* __restrict__ batch,
    int* __restrict__ gstart, int N, int G) {
  int i = blockIdx.x * 256 + threadIdx.x;
  if (i >= N) return;
  int b = batch[i];
  if (i == 0) { for (int g = 0; g <= b; g++) gstart[g] = 0; }
  else { int pb = batch[i - 1]; for (int g = pb + 1; g <= b; g++) gstart[g] = i; }
  if (i == N - 1) { for (int g = b + 1; g <= G; g++) gstart[g] = N; }
}

// ---------------- fp32 -> bf16 table ----------------
__global__ __launch_bounds__(256) void k_cvt(const float* __restrict__ src,
    unsigned short* __restrict__ dstb, int n) {
  int i = blockIdx.x * 256 + threadIdx.x;
  if (i < n) dstb[i] = f2bf(src[i]);
}

// ---------------- weights -> bf16, transposed to [mat][n][k] ----------------
__global__ __launch_bounds__(256) void k_cvt_w(const float* __restrict__ root,
    const float* __restrict__ W, unsigned short* __restrict__ wb) {
  int idx = blockIdx.x * 256 + threadIdx.x;   // 4*65536
  if (idx >= 4 * 65536) return;
  int mat = idx >> 16, rem = idx & 65535;
  int n = rem >> 8, k = rem & 255;
  const float* s = (mat == 0) ? root : (W + (size_t)(mat - 1) * 65536);
  wb[idx] = f2bf(s[k * 256 + n]);
}

// ---------------- relation aggregation: out[r*N+i] = invc * sum h[src] -----
__global__ __launch_bounds__(256) void k_agg(const unsigned short* __restrict__ h,
    const int* __restrict__ gidx, const int* __restrict__ es,
    const int* __restrict__ off, unsigned short* __restrict__ out, int RN) {
  int id = blockIdx.x * 4 + (threadIdx.x >> 6);
  if (id >= RN) return;
  int lane = threadIdx.x & 63;
  int lo = off[id], hi = off[id + 1];
  float inv = 1.0f / (float)((hi - lo) > 0 ? (hi - lo) : 1);
  float a0 = 0.f, a1 = 0.f, a2 = 0.f, a3 = 0.f;
  for (int p = lo; p < hi; ++p) {
    int s = es[p];
    int row = gidx ? gidx[s] : s;
    ushort4 v = *(const ushort4*)(h + (size_t)row * D + lane * 4);
    a0 += bf2f(v.x); a1 += bf2f(v.y); a2 += bf2f(v.z); a3 += bf2f(v.w);
  }
  ushort4 o;
  o.x = f2bf(a0 * inv); o.y = f2bf(a1 * inv);
  o.z = f2bf(a2 * inv); o.w = f2bf(a3 * inv);
  *(ushort4*)(out + (size_t)id * D + lane * 4) = o;
}

// ---------------- fused K=1024 bf16 MFMA GEMM, 128-row blocks --------------
// C[i,:] = relu(bias + Aroot[rowA(i)]@Wb[0] + sum_r agg[r*N+i]@Wb[r+1])
// 128 rows x 256 cols per block. All staging loads coalesced: thread t
// covers row (t>>2)+64j, 16B chunk (t&3) -> lanes 0..3 = one row's 64 B.
// Step s+1's global loads issue right after barrier #2 (fly under MFMA).
__global__ __launch_bounds__(256) void k_lgemm(
    const unsigned short* __restrict__ Aroot, const int* __restrict__ gidx,
    const unsigned short* agg, const unsigned short* __restrict__ wb,
    const float* __restrict__ bias, unsigned short* Cout, int M, int N) {
  __shared__ unsigned short AsU[128 * 40];       // 10 KB [row][k] pad->40
  __shared__ unsigned short BsU[256 * 40];       // 20 KB [n][k]   pad->40
  const int tid = threadIdx.x;
  const int w = tid >> 6, lane = tid & 63;
  const int i0 = blockIdx.x * 128;
  const int ml = lane & 15, q = lane >> 4;

  const int srow = tid >> 2;       // 0..63
  const int schunk = tid & 3;      // 16B chunk within 64B k-slice
  // my two A rows: srow and srow+64
  int r0 = i0 + srow, r1 = i0 + srow + 64;
  int r0c = (r0 < M) ? r0 : (M - 1);
  int r1c = (r1 < M) ? r1 : (M - 1);
  const int rowA0 = gidx ? gidx[r0c] : r0c;
  const int rowA1 = gidx ? gidx[r1c] : r1c;

  // per-seg A base pointers for my two rows (+ chunk offset)
  const unsigned short* a0base[4];
  const unsigned short* a1base[4];
  a0base[0] = Aroot + (size_t)rowA0 * D + schunk * 8;
  a1base[0] = Aroot + (size_t)rowA1 * D + schunk * 8;
#pragma unroll
  for (int r = 0; r < 3; r++) {
    a0base[r + 1] = agg + ((size_t)r * N + r0c) * D + schunk * 8;
    a1base[r + 1] = agg + ((size_t)r * N + r1c) * D + schunk * 8;
  }

  floatx4 acc[8][4];
#pragma unroll
  for (int i = 0; i < 8; i++)
#pragma unroll
    for (int j = 0; j < 4; j++) acc[i][j] = (floatx4){0.f, 0.f, 0.f, 0.f};

  // prefetch registers (step 0)
  uint4 av0, av1, bv0, bv1, bv2, bv3;
  {
    av0 = *(const uint4*)(a0base[0]);
    av1 = *(const uint4*)(a1base[0]);
    const unsigned short* bb = wb + (size_t)srow * D + schunk * 8;
    bv0 = *(const uint4*)(bb);
    bv1 = *(const uint4*)(bb + 64 * D);
    bv2 = *(const uint4*)(bb + 128 * D);
    bv3 = *(const uint4*)(bb + 192 * D);
  }

  for (int step = 0; step < 32; ++step) {
    __syncthreads();   // previous step's LDS consumers done
    *(uint4*)&AsU[srow * 40 + schunk * 8] = av0;
    *(uint4*)&AsU[(srow + 64) * 40 + schunk * 8] = av1;
    *(uint4*)&BsU[srow * 40 + schunk * 8] = bv0;
    *(uint4*)&BsU[(srow + 64) * 40 + schunk * 8] = bv1;
    *(uint4*)&BsU[(srow + 128) * 40 + schunk * 8] = bv2;
    *(uint4*)&BsU[(srow + 192) * 40 + schunk * 8] = bv3;
    __syncthreads();

    // issue next step's loads now — they fly under the compute below
    {
      int ns = (step < 31) ? step + 1 : 31;
      int seg = ns >> 3, kloc = (ns & 7) * 32;
      av0 = *(const uint4*)(a0base[seg] + kloc);
      av1 = *(const uint4*)(a1base[seg] + kloc);
      const unsigned short* bb =
          wb + (size_t)seg * 65536 + (size_t)srow * D + schunk * 8 + kloc;
      bv0 = *(const uint4*)(bb);
      bv1 = *(const uint4*)(bb + 64 * D);
      bv2 = *(const uint4*)(bb + 128 * D);
      bv3 = *(const uint4*)(bb + 192 * D);
    }

    short8 aF[8], bF[4];
#pragma unroll
    for (int mi = 0; mi < 8; mi++)
      aF[mi] = *(const short8*)&AsU[(mi * 16 + ml) * 40 + q * 8];
#pragma unroll
    for (int ni = 0; ni < 4; ni++)
      bF[ni] = *(const short8*)&BsU[(w * 64 + ni * 16 + ml) * 40 + q * 8];
#pragma unroll
    for (int mi = 0; mi < 8; mi++)
#pragma unroll
      for (int ni = 0; ni < 4; ni++)
        acc[mi][ni] = __builtin_amdgcn_mfma_f32_16x16x32_bf16(
            aF[mi], bF[ni], acc[mi][ni], 0, 0, 0);
  }

  // epilogue: bias + ReLU + bf16; C/D layout col=lane&15, row=q*4+reg
  float bv[4];
#pragma unroll
  for (int ni = 0; ni < 4; ni++) bv[ni] = bias[w * 64 + ni * 16 + ml];
#pragma unroll
  for (int mi = 0; mi < 8; mi++) {
#pragma unroll
    for (int ni = 0; ni < 4; ni++) {
      int col = w * 64 + ni * 16 + ml;
#pragma unroll
      for (int j = 0; j < 4; j++) {
        int row = i0 + mi * 16 + q * 4 + j;
        if (row < M) {
          float v = fmaxf(acc[mi][ni][j] + bv[ni], 0.f);
          Cout[(size_t)row * D + col] = f2bf(v);
        }
      }
    }
  }
}

// ---------------- graph mean-pool (bf16 in, fp32 out) ----------------
__global__ __launch_bounds__(256) void k_pool(const unsigned short* __restrict__ h,
    const int* __restrict__ gstart, float* __restrict__ gmean, int G) {
  __shared__ float red[4][D];
  int g = blockIdx.x;
  int lo = gstart[g], hi = gstart[g + 1];
  int tid = threadIdx.x, wave = tid >> 6, lane = tid & 63;
  float a0 = 0.f, a1 = 0.f, a2 = 0.f, a3 = 0.f;
  for (int i = lo + wave; i < hi; i += 4) {
    ushort4 v = *(const ushort4*)(h + (size_t)i * D + lane * 4);
    a0 += bf2f(v.x); a1 += bf2f(v.y); a2 += bf2f(v.z); a3 += bf2f(v.w);
  }
  red[wave][lane * 4 + 0] = a0;
  red[wave][lane * 4 + 1] = a1;
  red[wave][lane * 4 + 2] = a2;
  red[wave][lane * 4 + 3] = a3;
  __syncthreads();
  float s = red[0][tid] + red[1][tid] + red[2][tid] + red[3][tid];
  float inv = (hi > lo) ? 1.0f / (float)(hi - lo) : 0.0f;
  gmean[(size_t)g * D + tid] = s * inv;
}

// ---------------- head ----------------
__global__ __launch_bounds__(256) void k_final(const float* __restrict__ gmean,
    const float* __restrict__ linW, const float* __restrict__ linb,
    float* __restrict__ out, int G) {
  int g = blockIdx.x * 4 + (threadIdx.x >> 6);
  if (g >= G) return;
  int lane = threadIdx.x & 63;
  float4 v = *(const float4*)(gmean + (size_t)g * D + lane * 4);
  float vv[4] = {v.x, v.y, v.z, v.w};
  float a0 = 0.f, a1 = 0.f, a2 = 0.f, a3 = 0.f;
#pragma unroll
  for (int j = 0; j < 4; j++) {
    float4 wv = *(const float4*)(linW + (lane * 4 + j) * 4);
    a0 = fmaf(vv[j], wv.x, a0);
    a1 = fmaf(vv[j], wv.y, a1);
    a2 = fmaf(vv[j], wv.z, a2);
    a3 = fmaf(vv[j], wv.w, a3);
  }
  for (int o = 32; o > 0; o >>= 1) {
    a0 += __shfl_down(a0, o, 64);
    a1 += __shfl_down(a1, o, 64);
    a2 += __shfl_down(a2, o, 64);
    a3 += __shfl_down(a3, o, 64);
  }
  if (lane == 0) {
    out[g * 4 + 0] = a0 + linb[0];
    out[g * 4 + 1] = a1 + linb[1];
    out[g * 4 + 2] = a2 + linb[2];
    out[g * 4 + 3] = a3 + linb[3];
  }
}

extern "C" void kernel_launch(void* const* d_in, const int* in_sizes, int n_in,
                              void* d_out, int out_size, void* d_ws, size_t ws_size,
                              hipStream_t stream) {
  const int*   x     = (const int*)d_in[0];
  const int*   ei    = (const int*)d_in[1];
  const int*   et    = (const int*)d_in[2];
  const int*   batch = (const int*)d_in[3];
  const float* table = (const float*)d_in[5];
  const float* W1    = (const float*)d_in[6];
  const float* root1 = (const float*)d_in[7];
  const float* b1    = (const float*)d_in[8];
  const float* W2    = (const float*)d_in[9];
  const float* root2 = (const float*)d_in[10];
  const float* b2    = (const float*)d_in[11];
  const float* linW  = (const float*)d_in[12];
  const float* linb  = (const float*)d_in[13];
  float* out = (float*)d_out;

  const int N = in_sizes[0];
  const int E = in_sizes[2];
  const int G = out_size / 4;
  const int VOC = in_sizes[5] / D;
  const int* src = ei;
  const int* dst = ei + E;
  const int RN = 3 * N;

  // ---- ws layout (~209 MB), same proven aliasing as rounds 5-6 ----
  char* wsb = (char*)d_ws;
  size_t pg = (size_t)N * D * 2;
  unsigned short* P0 = (unsigned short*)wsb;
  unsigned short* P1 = (unsigned short*)(wsb + pg);
  unsigned short* P3 = (unsigned short*)(wsb + 3 * pg);
  unsigned short* wb = (unsigned short*)(wsb + 4 * pg);  // 2 layers x 4 mats
  int*   off    = (int*)(wb + 2 * 4 * 65536);
  int*   es     = off + (RN + 1);
  int*   gstart = es + E;
  float* gmean  = (float*)(gstart + (G + 1));
  unsigned short* tableb = P3;          // alias
  int* cur  = (int*)P0;                 // alias
  int* bsum = cur + RN;                 // alias

  const int nb = (RN + SB - 1) / SB;    // 293 <= 1024

  // ---- CSR by (relation, dst) + graph bounds + dtype prep ----
  k_zero_i<<<(RN + 255) / 256, 256, 0, stream>>>(cur, RN);
  k_count_i<<<(E + 255) / 256, 256, 0, stream>>>(dst, et, cur, E, N);
  k_scan1<<<nb, 256, 0, stream>>>(cur, bsum, RN);
  k_scan2<<<1, 256, 0, stream>>>(bsum, nb, off + RN);
  k_scan3<<<nb, 256, 0, stream>>>(cur, bsum, off, cur, RN);
  k_place2<<<(E + 255) / 256, 256, 0, stream>>>(src, dst, et, cur, es, E, N);
  k_bounds<<<(N + 255) / 256, 256, 0, stream>>>(batch, gstart, N, G);
  k_cvt<<<(VOC * D + 255) / 256, 256, 0, stream>>>(table, tableb, VOC * D);
  k_cvt_w<<<(4 * 65536 + 255) / 256, 256, 0, stream>>>(root1, W1, wb);
  k_cvt_w<<<(4 * 65536 + 255) / 256, 256, 0, stream>>>(root2, W2, wb + 4 * 65536);

  const int gagg = (RN + 3) / 4;
  const int ggemm = (N + 127) / 128;

  // ---- layer 1 ----
  k_agg<<<gagg, 256, 0, stream>>>(tableb, x, es, off, P0, RN);
  k_lgemm<<<ggemm, 256, 0, stream>>>(tableb, x, P0, wb, b1, P0, N, N);
  // ---- layer 2 ----
  k_agg<<<gagg, 256, 0, stream>>>(P0, nullptr, es, off, P1, RN);
  k_lgemm<<<ggemm, 256, 0, stream>>>(P0, nullptr, P1, wb + 4 * 65536, b2, P1, N, N);

  // ---- pool + head ----
  k_pool<<<G, 256, 0, stream>>>(P1, gstart, gmean, G);
  k_final<<<(G + 3) / 4, 256, 0, stream>>>(gmean, linW, linb, out, G);
}

// Round 8
// 483.558 us; speedup vs baseline: 1.2736x; 1.2736x over previous
//
#include <hip/hip_runtime.h>

#define D 256
#define SB 1024
typedef __attribute__((ext_vector_type(8))) short short8;
typedef __attribute__((ext_vector_type(4))) float floatx4;

__device__ __forceinline__ unsigned short f2bf(float f) {
  unsigned int u = __float_as_uint(f);
  u = (u + 0x7FFF + ((u >> 16) & 1)) >> 16;   // RNE
  return (unsigned short)u;
}
__device__ __forceinline__ float bf2f(unsigned short h) {
  return __uint_as_float(((unsigned int)h) << 16);
}

// ---------------- setup kernels ----------------
__global__ __launch_bounds__(256) void k_zero_i(int* __restrict__ p, int n) {
  int i = blockIdx.x * 256 + threadIdx.x;
  if (i < n) p[i] = 0;
}

__global__ __launch_bounds__(256) void k_count_i(const int* __restrict__ dst,
    const int* __restrict__ et, int* __restrict__ cnt, int E, int N) {
  int e = blockIdx.x * 256 + threadIdx.x;
  if (e >= E) return;
  atomicAdd(&cnt[et[e] * N + dst[e]], 1);
}

__global__ __launch_bounds__(256) void k_scan1(const int* __restrict__ in,
    int* __restrict__ bsum, int n) {
  __shared__ int s[256];
  int base = blockIdx.x * SB, t = threadIdx.x;
  int a = 0;
#pragma unroll
  for (int j = 0; j < 4; j++) { int i = base + t * 4 + j; if (i < n) a += in[i]; }
  s[t] = a; __syncthreads();
  for (int o = 128; o > 0; o >>= 1) { if (t < o) s[t] += s[t + o]; __syncthreads(); }
  if (t == 0) bsum[blockIdx.x] = s[0];
}

// parallel single-block exclusive scan over bsum (nb <= 1024)
__global__ __launch_bounds__(256) void k_scan2(int* __restrict__ bsum, int nb,
    int* __restrict__ total_out) {
  __shared__ int s[256];
  int t = threadIdx.x;
  int v[4]; int a = 0;
#pragma unroll
  for (int j = 0; j < 4; j++) {
    int i = t * 4 + j;
    v[j] = (i < nb) ? bsum[i] : 0;
    a += v[j];
  }
  s[t] = a; __syncthreads();
  for (int o = 1; o < 256; o <<= 1) {
    int x_ = (t >= o) ? s[t - o] : 0;
    __syncthreads();
    s[t] += x_;
    __syncthreads();
  }
  int excl = (t > 0) ? s[t - 1] : 0;
#pragma unroll
  for (int j = 0; j < 4; j++) {
    int i = t * 4 + j;
    if (i < nb) { bsum[i] = excl; excl += v[j]; }
  }
  if (t == 255) *total_out = s[255];
}

__global__ __launch_bounds__(256) void k_scan3(const int* __restrict__ in,
    const int* __restrict__ bsum, int* __restrict__ off, int* __restrict__ cur,
    int n) {
  __shared__ int s[256];
  int base = blockIdx.x * SB, t = threadIdx.x;
  int v[4]; int a = 0;
#pragma unroll
  for (int j = 0; j < 4; j++) {
    int i = base + t * 4 + j;
    v[j] = (i < n) ? in[i] : 0;
    a += v[j];
  }
  s[t] = a; __syncthreads();
  for (int o = 1; o < 256; o <<= 1) {
    int x_ = (t >= o) ? s[t - o] : 0;
    __syncthreads();
    s[t] += x_;
    __syncthreads();
  }
  int excl = (t > 0 ? s[t - 1] : 0) + bsum[blockIdx.x];
#pragma unroll
  for (int j = 0; j < 4; j++) {
    int i = base + t * 4 + j;
    if (i < n) { off[i] = excl; cur[i] = excl; excl += v[j]; }
  }
}

__global__ __launch_bounds__(256) void k_place2(const int* __restrict__ src,
    const int* __restrict__ dst, const int* __restrict__ et,
    int* __restrict__ cur, int* __restrict__ es, int E, int N) {
  int e = blockIdx.x * 256 + threadIdx.x;
  if (e >= E) return;
  int pos = atomicAdd(&cur[et[e] * N + dst[e]], 1);
  es[pos] = src[e];
}

__global__ __launch_bounds__(256) void k_bounds(const int* __restrict__ batch,
    int* __restrict__ gstart, int N, int G) {
  int i = blockIdx.x * 256 + threadIdx.x;
  if (i >= N) return;
  int b = batch[i];
  if (i == 0) { for (int g = 0; g <= b; g++) gstart[g] = 0; }
  else { int pb = batch[i - 1]; for (int g = pb + 1; g <= b; g++) gstart[g] = i; }
  if (i == N - 1) { for (int g = b + 1; g <= G; g++) gstart[g] = N; }
}

// ---------------- fp32 -> bf16 table ----------------
__global__ __launch_bounds__(256) void k_cvt(const float* __restrict__ src,
    unsigned short* __restrict__ dstb, int n) {
  int i = blockIdx.x * 256 + threadIdx.x;
  if (i < n) dstb[i] = f2bf(src[i]);
}

// ---------------- weights -> bf16, transposed to [mat][n][k] ----------------
__global__ __launch_bounds__(256) void k_cvt_w(const float* __restrict__ root,
    const float* __restrict__ W, unsigned short* __restrict__ wb) {
  int idx = blockIdx.x * 256 + threadIdx.x;   // 4*65536
  if (idx >= 4 * 65536) return;
  int mat = idx >> 16, rem = idx & 65535;
  int n = rem >> 8, k = rem & 255;
  const float* s = (mat == 0) ? root : (W + (size_t)(mat - 1) * 65536);
  wb[idx] = f2bf(s[k * 256 + n]);
}

// ---------------- relation aggregation: out[r*N+i] = invc * sum h[src] -----
__global__ __launch_bounds__(256) void k_agg(const unsigned short* __restrict__ h,
    const int* __restrict__ gidx, const int* __restrict__ es,
    const int* __restrict__ off, unsigned short* __restrict__ out, int RN) {
  int id = blockIdx.x * 4 + (threadIdx.x >> 6);
  if (id >= RN) return;
  int lane = threadIdx.x & 63;
  int lo = off[id], hi = off[id + 1];
  float inv = 1.0f / (float)((hi - lo) > 0 ? (hi - lo) : 1);
  float a0 = 0.f, a1 = 0.f, a2 = 0.f, a3 = 0.f;
  for (int p = lo; p < hi; ++p) {
    int s = es[p];
    int row = gidx ? gidx[s] : s;
    ushort4 v = *(const ushort4*)(h + (size_t)row * D + lane * 4);
    a0 += bf2f(v.x); a1 += bf2f(v.y); a2 += bf2f(v.z); a3 += bf2f(v.w);
  }
  ushort4 o;
  o.x = f2bf(a0 * inv); o.y = f2bf(a1 * inv);
  o.z = f2bf(a2 * inv); o.w = f2bf(a3 * inv);
  *(ushort4*)(out + (size_t)id * D + lane * 4) = o;
}

// ---------------- fused K=1024 bf16 MFMA GEMM, 128x256 block, 8 waves ------
// C[i,:] = relu(bias + Aroot[rowA(i)]@Wb[0] + sum_r agg[r*N+i]@Wb[r+1])
// 512 thr = 8 waves in 2x4 grid; wave tile 64x64 (4x4 frags of 16x16x32).
// LDS per k32-step: A 8KB + B 16KB writes, 64KB reads / 256 MFMA = 344 B/MFMA
// (vs 812 in the 64x256 shape) -> LDS-bound ceiling ~45% MfmaUtil.
// Full-width 256 cols keeps the C-over-input page aliasing safe.
__global__ __launch_bounds__(512) void k_lgemm(
    const unsigned short* __restrict__ Aroot, const int* __restrict__ gidx,
    const unsigned short* agg, const unsigned short* __restrict__ wb,
    const float* __restrict__ bias, unsigned short* Cout, int M, int N) {
  __shared__ unsigned short AsU[128 * 40];       // 10 KB [row][k] pad->40
  __shared__ unsigned short BsU[256 * 40];       // 20 KB [n][k]   pad->40
  const int tid = threadIdx.x;
  const int w = tid >> 6, lane = tid & 63;
  const int wr = w >> 2, wc = w & 3;             // wave grid 2x4
  const int i0 = blockIdx.x * 128;
  const int ml = lane & 15, q = lane >> 4;

  const int srow = tid >> 2;       // 0..127
  const int schunk = tid & 3;      // 16B chunk within 64B k-slice
  int r0 = i0 + srow;
  int r0c = (r0 < M) ? r0 : (M - 1);
  const int rowA0 = gidx ? gidx[r0c] : r0c;

  const unsigned short* a0base[4];
  a0base[0] = Aroot + (size_t)rowA0 * D + schunk * 8;
#pragma unroll
  for (int r = 0; r < 3; r++)
    a0base[r + 1] = agg + ((size_t)r * N + r0c) * D + schunk * 8;

  floatx4 acc[4][4];
#pragma unroll
  for (int i = 0; i < 4; i++)
#pragma unroll
    for (int j = 0; j < 4; j++) acc[i][j] = (floatx4){0.f, 0.f, 0.f, 0.f};

  // prefetch registers (step 0)
  uint4 av0, bv0, bv1;
  {
    av0 = *(const uint4*)(a0base[0]);
    const unsigned short* bb = wb + (size_t)srow * D + schunk * 8;
    bv0 = *(const uint4*)(bb);
    bv1 = *(const uint4*)(bb + 128 * D);
  }

  for (int step = 0; step < 32; ++step) {
    __syncthreads();   // previous step's LDS consumers done
    *(uint4*)&AsU[srow * 40 + schunk * 8] = av0;
    *(uint4*)&BsU[srow * 40 + schunk * 8] = bv0;
    *(uint4*)&BsU[(srow + 128) * 40 + schunk * 8] = bv1;
    __syncthreads();

    // issue next step's loads now — they fly under the compute below
    {
      int ns = (step < 31) ? step + 1 : 31;
      int seg = ns >> 3, kloc = (ns & 7) * 32;
      av0 = *(const uint4*)(a0base[seg] + kloc);
      const unsigned short* bb =
          wb + (size_t)seg * 65536 + (size_t)srow * D + schunk * 8 + kloc;
      bv0 = *(const uint4*)(bb);
      bv1 = *(const uint4*)(bb + 128 * D);
    }

    short8 aF[4], bF[4];
#pragma unroll
    for (int mi = 0; mi < 4; mi++)
      aF[mi] = *(const short8*)&AsU[(wr * 64 + mi * 16 + ml) * 40 + q * 8];
#pragma unroll
    for (int ni = 0; ni < 4; ni++)
      bF[ni] = *(const short8*)&BsU[(wc * 64 + ni * 16 + ml) * 40 + q * 8];
#pragma unroll
    for (int mi = 0; mi < 4; mi++)
#pragma unroll
      for (int ni = 0; ni < 4; ni++)
        acc[mi][ni] = __builtin_amdgcn_mfma_f32_16x16x32_bf16(
            aF[mi], bF[ni], acc[mi][ni], 0, 0, 0);
  }

  // epilogue: bias + ReLU + bf16; C/D layout col=lane&15, row=q*4+reg
  float bv[4];
#pragma unroll
  for (int ni = 0; ni < 4; ni++) bv[ni] = bias[wc * 64 + ni * 16 + ml];
#pragma unroll
  for (int mi = 0; mi < 4; mi++) {
#pragma unroll
    for (int ni = 0; ni < 4; ni++) {
      int col = wc * 64 + ni * 16 + ml;
#pragma unroll
      for (int j = 0; j < 4; j++) {
        int row = i0 + wr * 64 + mi * 16 + q * 4 + j;
        if (row < M) {
          float v = fmaxf(acc[mi][ni][j] + bv[ni], 0.f);
          Cout[(size_t)row * D + col] = f2bf(v);
        }
      }
    }
  }
}

// ---------------- graph mean-pool (bf16 in, fp32 out) ----------------
__global__ __launch_bounds__(256) void k_pool(const unsigned short* __restrict__ h,
    const int* __restrict__ gstart, float* __restrict__ gmean, int G) {
  __shared__ float red[4][D];
  int g = blockIdx.x;
  int lo = gstart[g], hi = gstart[g + 1];
  int tid = threadIdx.x, wave = tid >> 6, lane = tid & 63;
  float a0 = 0.f, a1 = 0.f, a2 = 0.f, a3 = 0.f;
  for (int i = lo + wave; i < hi; i += 4) {
    ushort4 v = *(const ushort4*)(h + (size_t)i * D + lane * 4);
    a0 += bf2f(v.x); a1 += bf2f(v.y); a2 += bf2f(v.z); a3 += bf2f(v.w);
  }
  red[wave][lane * 4 + 0] = a0;
  red[wave][lane * 4 + 1] = a1;
  red[wave][lane * 4 + 2] = a2;
  red[wave][lane * 4 + 3] = a3;
  __syncthreads();
  float s = red[0][tid] + red[1][tid] + red[2][tid] + red[3][tid];
  float inv = (hi > lo) ? 1.0f / (float)(hi - lo) : 0.0f;
  gmean[(size_t)g * D + tid] = s * inv;
}

// ---------------- head ----------------
__global__ __launch_bounds__(256) void k_final(const float* __restrict__ gmean,
    const float* __restrict__ linW, const float* __restrict__ linb,
    float* __restrict__ out, int G) {
  int g = blockIdx.x * 4 + (threadIdx.x >> 6);
  if (g >= G) return;
  int lane = threadIdx.x & 63;
  float4 v = *(const float4*)(gmean + (size_t)g * D + lane * 4);
  float vv[4] = {v.x, v.y, v.z, v.w};
  float a0 = 0.f, a1 = 0.f, a2 = 0.f, a3 = 0.f;
#pragma unroll
  for (int j = 0; j < 4; j++) {
    float4 wv = *(const float4*)(linW + (lane * 4 + j) * 4);
    a0 = fmaf(vv[j], wv.x, a0);
    a1 = fmaf(vv[j], wv.y, a1);
    a2 = fmaf(vv[j], wv.z, a2);
    a3 = fmaf(vv[j], wv.w, a3);
  }
  for (int o = 32; o > 0; o >>= 1) {
    a0 += __shfl_down(a0, o, 64);
    a1 += __shfl_down(a1, o, 64);
    a2 += __shfl_down(a2, o, 64);
    a3 += __shfl_down(a3, o, 64);
  }
  if (lane == 0) {
    out[g * 4 + 0] = a0 + linb[0];
    out[g * 4 + 1] = a1 + linb[1];
    out[g * 4 + 2] = a2 + linb[2];
    out[g * 4 + 3] = a3 + linb[3];
  }
}

extern "C" void kernel_launch(void* const* d_in, const int* in_sizes, int n_in,
                              void* d_out, int out_size, void* d_ws, size_t ws_size,
                              hipStream_t stream) {
  const int*   x     = (const int*)d_in[0];
  const int*   ei    = (const int*)d_in[1];
  const int*   et    = (const int*)d_in[2];
  const int*   batch = (const int*)d_in[3];
  const float* table = (const float*)d_in[5];
  const float* W1    = (const float*)d_in[6];
  const float* root1 = (const float*)d_in[7];
  const float* b1    = (const float*)d_in[8];
  const float* W2    = (const float*)d_in[9];
  const float* root2 = (const float*)d_in[10];
  const float* b2    = (const float*)d_in[11];
  const float* linW  = (const float*)d_in[12];
  const float* linb  = (const float*)d_in[13];
  float* out = (float*)d_out;

  const int N = in_sizes[0];
  const int E = in_sizes[2];
  const int G = out_size / 4;
  const int VOC = in_sizes[5] / D;
  const int* src = ei;
  const int* dst = ei + E;
  const int RN = 3 * N;

  // ---- ws layout (~209 MB), same proven aliasing as rounds 5-7 ----
  char* wsb = (char*)d_ws;
  size_t pg = (size_t)N * D * 2;
  unsigned short* P0 = (unsigned short*)wsb;
  unsigned short* P1 = (unsigned short*)(wsb + pg);
  unsigned short* P3 = (unsigned short*)(wsb + 3 * pg);
  unsigned short* wb = (unsigned short*)(wsb + 4 * pg);  // 2 layers x 4 mats
  int*   off    = (int*)(wb + 2 * 4 * 65536);
  int*   es     = off + (RN + 1);
  int*   gstart = es + E;
  float* gmean  = (float*)(gstart + (G + 1));
  unsigned short* tableb = P3;          // alias
  int* cur  = (int*)P0;                 // alias
  int* bsum = cur + RN;                 // alias

  const int nb = (RN + SB - 1) / SB;    // 293 <= 1024

  // ---- CSR by (relation, dst) + graph bounds + dtype prep ----
  k_zero_i<<<(RN + 255) / 256, 256, 0, stream>>>(cur, RN);
  k_count_i<<<(E + 255) / 256, 256, 0, stream>>>(dst, et, cur, E, N);
  k_scan1<<<nb, 256, 0, stream>>>(cur, bsum, RN);
  k_scan2<<<1, 256, 0, stream>>>(bsum, nb, off + RN);
  k_scan3<<<nb, 256, 0, stream>>>(cur, bsum, off, cur, RN);
  k_place2<<<(E + 255) / 256, 256, 0, stream>>>(src, dst, et, cur, es, E, N);
  k_bounds<<<(N + 255) / 256, 256, 0, stream>>>(batch, gstart, N, G);
  k_cvt<<<(VOC * D + 255) / 256, 256, 0, stream>>>(table, tableb, VOC * D);
  k_cvt_w<<<(4 * 65536 + 255) / 256, 256, 0, stream>>>(root1, W1, wb);
  k_cvt_w<<<(4 * 65536 + 255) / 256, 256, 0, stream>>>(root2, W2, wb + 4 * 65536);

  const int gagg = (RN + 3) / 4;
  const int ggemm = (N + 127) / 128;

  // ---- layer 1 ----
  k_agg<<<gagg, 256, 0, stream>>>(tableb, x, es, off, P0, RN);
  k_lgemm<<<ggemm, 512, 0, stream>>>(tableb, x, P0, wb, b1, P0, N, N);
  // ---- layer 2 ----
  k_agg<<<gagg, 256, 0, stream>>>(P0, nullptr, es, off, P1, RN);
  k_lgemm<<<ggemm, 512, 0, stream>>>(P0, nullptr, P1, wb + 4 * 65536, b2, P1, N, N);

  // ---- pool + head ----
  k_pool<<<G, 256, 0, stream>>>(P1, gstart, gmean, G);
  k_final<<<(G + 3) / 4, 256, 0, stream>>>(gmean, linW, linb, out, G);
}